// Round 13
// baseline (2219.732 us; speedup 1.0000x reference)
//
#include <hip/hip_runtime.h>

#define NT 512   // timesteps
#define FB 128   // feature bins
#define HD 256   // L1 == L2 hidden
#define NC 10
#define NG 32    // groups
#define GR 8     // batch rows per group

typedef __attribute__((ext_vector_type(8))) short bf16x8;
typedef __attribute__((ext_vector_type(4))) float f32x4;
typedef __attribute__((ext_vector_type(4))) unsigned u32x4;

static __device__ __forceinline__ short f2bf(float f){
  union { float f; unsigned u; } v; v.f = f;
  return (short)((v.u + 0x7fffu + ((v.u >> 16) & 1u)) >> 16);  // RNE
}
static __device__ __forceinline__ float bf2f(short h){
  union { unsigned u; float f; } v; v.u = ((unsigned)(unsigned short)h) << 16;
  return v.f;
}
static __device__ __forceinline__ float quantw(float w){
  return fminf(fmaxf(rintf(w * 8.0f) * 0.125f, -1.0f), 1.0f);  // exact in bf16
}
static __device__ __forceinline__ bf16x8 loadqw8(const float* __restrict__ p){
  bf16x8 v;
#pragma unroll
  for (int j = 0; j < 8; ++j) v[j] = f2bf(quantw(p[j]));
  return v;
}
static __device__ __forceinline__ void split8(f32x4 a, f32x4 b, bf16x8& hi, bf16x8& lo){
  float v0[4] = {a[0],a[1],a[2],a[3]}, v1[4] = {b[0],b[1],b[2],b[3]};
#pragma unroll
  for (int j = 0; j < 4; ++j){
    short h = f2bf(v0[j]); hi[j] = h; lo[j] = f2bf(v0[j] - bf2f(h));
  }
#pragma unroll
  for (int j = 0; j < 4; ++j){
    short h = f2bf(v1[j]); hi[4+j] = h; lo[4+j] = f2bf(v1[j] - bf2f(h));
  }
}

// ---- epoch-in-band messaging over sc1 (R9-proven mechanism) ----
static __device__ __forceinline__ void st_msg(unsigned* p, short hb, short lb, unsigned ep){
  __attribute__((ext_vector_type(2))) unsigned w;
  w[0] = (((unsigned)(unsigned short)hb) << 16) | ep;
  w[1] = (((unsigned)(unsigned short)lb) << 16) | ep;
  asm volatile("global_store_dwordx2 %0, %1, off sc1" :: "v"(p), "v"(w) : "memory");
}
// blocking gather with retry (fallback path; drains vmcnt(0))
static __device__ __forceinline__ void gather8(const unsigned* p, unsigned ep, bf16x8& hv, bf16x8& lv){
  u32x4 a, b, c, d;
  for (;;){
    asm volatile("global_load_dwordx4 %0, %4, off sc1\n\t"
                 "global_load_dwordx4 %1, %4, off offset:16 sc1\n\t"
                 "global_load_dwordx4 %2, %4, off offset:32 sc1\n\t"
                 "global_load_dwordx4 %3, %4, off offset:48 sc1\n\t"
                 "s_waitcnt vmcnt(0)"
                 : "=&v"(a), "=&v"(b), "=&v"(c), "=&v"(d) : "v"(p) : "memory");
    unsigned m = (a[0]^ep)|(a[1]^ep)|(a[2]^ep)|(a[3]^ep)
               | (b[0]^ep)|(b[1]^ep)|(b[2]^ep)|(b[3]^ep)
               | (c[0]^ep)|(c[1]^ep)|(c[2]^ep)|(c[3]^ep)
               | (d[0]^ep)|(d[1]^ep)|(d[2]^ep)|(d[3]^ep);
    if ((m & 0xffffu) == 0u) break;
  }
  hv[0]=(short)(a[0]>>16); lv[0]=(short)(a[1]>>16);
  hv[1]=(short)(a[2]>>16); lv[1]=(short)(a[3]>>16);
  hv[2]=(short)(b[0]>>16); lv[2]=(short)(b[1]>>16);
  hv[3]=(short)(b[2]>>16); lv[3]=(short)(b[3]>>16);
  hv[4]=(short)(c[0]>>16); lv[4]=(short)(c[1]>>16);
  hv[5]=(short)(c[2]>>16); lv[5]=(short)(c[3]>>16);
  hv[6]=(short)(d[0]>>16); lv[6]=(short)(d[1]>>16);
  hv[7]=(short)(d[2]>>16); lv[7]=(short)(d[3]>>16);
}
static __device__ __forceinline__ bool chk_unpack(u32x4 a, u32x4 b, u32x4 c, u32x4 d,
                                                  unsigned ep, bf16x8& hv, bf16x8& lv){
  unsigned m = (a[0]^ep)|(a[1]^ep)|(a[2]^ep)|(a[3]^ep)
             | (b[0]^ep)|(b[1]^ep)|(b[2]^ep)|(b[3]^ep)
             | (c[0]^ep)|(c[1]^ep)|(c[2]^ep)|(c[3]^ep)
             | (d[0]^ep)|(d[1]^ep)|(d[2]^ep)|(d[3]^ep);
  if ((m & 0xffffu) != 0u) return false;
  hv[0]=(short)(a[0]>>16); lv[0]=(short)(a[1]>>16);
  hv[1]=(short)(a[2]>>16); lv[1]=(short)(a[3]>>16);
  hv[2]=(short)(b[0]>>16); lv[2]=(short)(b[1]>>16);
  hv[3]=(short)(b[2]>>16); lv[3]=(short)(b[3]>>16);
  hv[4]=(short)(c[0]>>16); lv[4]=(short)(c[1]>>16);
  hv[5]=(short)(c[2]>>16); lv[5]=(short)(c[3]>>16);
  hv[6]=(short)(d[0]>>16); lv[6]=(short)(d[1]>>16);
  hv[7]=(short)(d[2]>>16); lv[7]=(short)(d[3]>>16);
  return true;
}

// issue-only loads (no waitcnt) — T14 split
#define ISSUE_G8(P,A,B,C,D) \
  asm volatile("global_load_dwordx4 %0, %4, off sc1\n\t" \
               "global_load_dwordx4 %1, %4, off offset:16 sc1\n\t" \
               "global_load_dwordx4 %2, %4, off offset:32 sc1\n\t" \
               "global_load_dwordx4 %3, %4, off offset:48 sc1" \
               : "=&v"(A),"=&v"(B),"=&v"(C),"=&v"(D) : "v"(P) : "memory")
#define ISSUE_X2(P,A,B) \
  asm volatile("global_load_dwordx4 %0, %2, off\n\t" \
               "global_load_dwordx4 %1, %2, off offset:16" \
               : "=&v"(A),"=&v"(B) : "v"(P) : "memory")
// counted wait; "+v" rebinds force def-use ordering; sched_barrier per rule #18
#define WAITV4(N,A,B,C,D) do{ \
  asm volatile("s_waitcnt vmcnt(" #N ")" : "+v"(A),"+v"(B),"+v"(C),"+v"(D) :: "memory"); \
  __builtin_amdgcn_sched_barrier(0); }while(0)
// raw barrier: LDS ordering WITHOUT vmcnt drain (no sc1 store-ack stalls)
#define BARRIER() do{ asm volatile("s_waitcnt lgkmcnt(0)" ::: "memory"); \
  __builtin_amdgcn_s_barrier(); asm volatile("" ::: "memory"); }while(0)

// 256 blocks x 256 threads, 1 block/CU. gp = bid&31, sb = bid>>5 (same-XCD peers).
// RE-PHASED pipeline: iteration t = { wait h2(t-1); L2-h2half + head(t-1) (g1 in
// flight); wait h1(t) [posted LAST iter -> full-iter slack]; L2-h1half -> post
// h2(t); L1(t+1) -> post h1(t+1); issue next gathers }. Both exchanges now have
// ~a full iteration of slack; only 2 counted waits/iter, both wave-uniform.
__global__ __launch_bounds__(256, 1)
void egru_persistent(const float* __restrict__ xg,
                     const float* __restrict__ h1ig, const float* __restrict__ h2ig,
                     const float* __restrict__ W1g, const float* __restrict__ b1g,
                     const float* __restrict__ W2g, const float* __restrict__ b2g,
                     const float* __restrict__ W3g, const float* __restrict__ b3g,
                     const float* __restrict__ W4g, const float* __restrict__ b4g,
                     float* __restrict__ outg, float* __restrict__ wsf)
{
  const int tid = threadIdx.x;
  const int gp  = blockIdx.x & 31;
  const int sb  = blockIdx.x >> 5;
  const int wv  = tid >> 6;
  const int ln  = tid & 15;
  const int lk  = (tid >> 4) & 3;
  const int rz  = sb * 32;

  __shared__ __align__(16) short inX [16*128];  // x(t+1); rows 0-7 hi, 8-15 lo; 256 B/row
  __shared__ __align__(16) short inH1[16*256];  // h1(t); 512 B/row
  __shared__ __align__(16) short inH2[16*256];  // h2(t-1); 512 B/row
  __shared__ float aldsA[64][17];
  __shared__ float aldsB[64][17];
  __shared__ float h1own[32][GR];
  __shared__ float h2own[32][GR];
  __shared__ float h3p[128], h3q[128], h3row[128];
  __shared__ float ytmp[16];
  __shared__ float W4L[1344];                   // skewed: idx = c*134 + (k>>5)*33 + (k&31)
  __shared__ float b1s[64], b2s[64], b3L[128], b4L[10];

  unsigned* h1buf = reinterpret_cast<unsigned*>(wsf);
  unsigned* h2buf = h1buf + 262144;

  bf16x8 w1f[12], w2f[16], w3f[2][8];
  {
    const int arow = (wv < 2) ? (rz + wv*16 + ln) : (256 + rz + (wv-2)*16 + ln);
#pragma unroll
    for (int ks = 0; ks < 12; ++ks) w1f[ks] = loadqw8(W1g + arow*384 + ks*32 + lk*8);
#pragma unroll
    for (int ks = 0; ks < 16; ++ks) w2f[ks] = loadqw8(W2g + arow*512 + ks*32 + lk*8);
#pragma unroll
    for (int tl = 0; tl < 2; ++tl)
#pragma unroll
      for (int ks = 0; ks < 8; ++ks)
        w3f[tl][ks] = loadqw8(W3g + (wv*32 + tl*16 + ln)*256 + ks*32 + lk*8);
  }

  if (tid < 64){
    int grow = (tid < 32) ? (rz + tid) : (256 + rz + (tid - 32));
    b1s[tid] = b1g[grow];
    b2s[tid] = b2g[grow];
  }
  if (tid < 128) b3L[tid] = b3g[tid];
  if (tid < 10)  b4L[tid] = b4g[tid];
  for (int i = tid; i < 1280; i += 256){
    int c = i >> 7, k = i & 127;
    W4L[c*134 + (k>>5)*33 + (k&31)] = quantw(W4g[i]);
  }

  const int ur = tid >> 5, uc = tid & 31;   // (batch row, dim/chunk) mapping, 8x32
  {
    bf16x8 hv, lv;
    const float* p1 = h1ig + (size_t)(gp*GR + ur)*HD + uc*8;
    split8(*(const f32x4*)p1, *(const f32x4*)(p1+4), hv, lv);
    *(bf16x8*)((char*)inH1 + ur*512     + ((uc*16) ^ ((ur&7)<<4))) = hv;
    *(bf16x8*)((char*)inH1 + (ur+8)*512 + ((uc*16) ^ ((ur&7)<<4))) = lv;
    const float* p2 = h2ig + (size_t)(gp*GR + ur)*HD + uc*8;
    split8(*(const f32x4*)p2, *(const f32x4*)(p2+4), hv, lv);
    *(bf16x8*)((char*)inH2 + ur*512     + ((uc*16) ^ ((ur&7)<<4))) = hv;
    *(bf16x8*)((char*)inH2 + (ur+8)*512 + ((uc*16) ^ ((ur&7)<<4))) = lv;
    h1own[uc][ur] = h1ig[(size_t)(gp*GR+ur)*HD + rz + uc];
    h2own[uc][ur] = h2ig[(size_t)(gp*GR+ur)*HD + rz + uc];
  }
  const int xr = tid >> 4, xf = tid & 15;
  const int xrl = xr & 7;                   // clamped row: ALL threads load (uniform vmcnt)
  if (xr < 8){
    const float* px = xg + ((size_t)(gp*GR + xr)*NT + 0)*FB + xf*8;
    bf16x8 hv, lv;
    split8(*(const f32x4*)px, *(const f32x4*)(px+4), hv, lv);
    *(bf16x8*)((char*)inX + xr*256     + ((xf*16) ^ ((xr&7)<<4))) = hv;
    *(bf16x8*)((char*)inX + (xr+8)*256 + ((xf*16) ^ ((xr&7)<<4))) = lv;
  }
  __syncthreads();   // full drain at init boundary (intentional)

  // ---- prologue: L1(0) -> h1(0), post (epoch 1, slot 0); issue x(1) + g1(h1(0)) ----
  {
    f32x4 acc1 = {0.f,0.f,0.f,0.f};
#pragma unroll
    for (int j = 0; j < 4; ++j){
      bf16x8 fx = *(bf16x8*)((char*)inX + ln*256 + ((j*64 + lk*16) ^ ((ln&7)<<4)));
      acc1 = __builtin_amdgcn_mfma_f32_16x16x32_bf16(w1f[j], fx, acc1, 0, 0, 0);
    }
#pragma unroll
    for (int j = 0; j < 8; ++j){
      bf16x8 fh = *(bf16x8*)((char*)inH1 + ln*512 + ((j*64 + lk*16) ^ ((ln&7)<<4)));
      acc1 = __builtin_amdgcn_mfma_f32_16x16x32_bf16(w1f[4+j], fh, acc1, 0, 0, 0);
    }
#pragma unroll
    for (int r4 = 0; r4 < 4; ++r4)
      aldsA[wv*16 + lk*4 + r4][ln] = acc1[r4];
    BARRIER();
    float az = aldsA[uc][ur]    + aldsA[uc][ur+8]    + b1s[uc];
    float ac = aldsA[32+uc][ur] + aldsA[32+uc][ur+8] + b1s[32+uc];
    float z  = 0.5f*(az/(1.0f+fabsf(az)) + 1.0f);
    float cd = ac/(1.0f+fabsf(ac));
    float hn = z*h1own[uc][ur] + (1.0f - z)*cd;
    h1own[uc][ur] = hn;
    short hb = f2bf(hn), lb = f2bf(hn - bf2f(hb));
    st_msg(h1buf + (unsigned)(gp*GR)*512u + ur*512 + (rz + uc)*2, hb, lb, 1u);
  }
  u32x4 g1a, g1b, g1c, g1d, g2a, g2b, g2c, g2d;
  f32x4 xa = {0,0,0,0}, xb = {0,0,0,0};
  {
    const float* px = xg + ((size_t)(gp*GR + xrl)*NT + 1)*FB + xf*8;
    ISSUE_X2(px, xa, xb);
  }
  ISSUE_G8(h1buf + (unsigned)(gp*GR)*512u + ur*512 + uc*16, g1a, g1b, g1c, g1d);

  for (int t = 0; t < NT; ++t){
    unsigned* h1r = h1buf + (unsigned)(t & 1)*131072u + (unsigned)(gp*GR)*512u;       // h1(t), ep t+1
    unsigned* h1w = h1buf + (unsigned)((t+1) & 1)*131072u + (unsigned)(gp*GR)*512u;   // h1(t+1) write
    unsigned* h2w = h2buf + (unsigned)(t & 1)*131072u + (unsigned)(gp*GR)*512u;       // h2(t) write
    unsigned* h2r = h2buf + (unsigned)((t + 1) & 1)*131072u + (unsigned)(gp*GR)*512u; // h2(t-1), ep t
    const bool haveX = (t + 1) < NT;   // block-uniform

    // ---- S1: consume h2(t-1) (posted last iter -> ~full-iter slack) ----
    if (t > 0){
      // outstanding oldest->newest: stH2(t-1), stH1(t), [outg wave0], g2 x4, [x x2 if t<NT-1]
      if (t < NT-1) WAITV4(2, g2a, g2b, g2c, g2d);
      else          WAITV4(0, g2a, g2b, g2c, g2d);
      bf16x8 hv, lv;
      if (!chk_unpack(g2a, g2b, g2c, g2d, (unsigned)t, hv, lv))
        gather8(&h2r[ur*512 + uc*16], (unsigned)t, hv, lv);
      *(bf16x8*)((char*)inH2 + ur*512     + ((uc*16) ^ ((ur&7)<<4))) = hv;
      *(bf16x8*)((char*)inH2 + (ur+8)*512 + ((uc*16) ^ ((ur&7)<<4))) = lv;
      BARRIER();
    }

    // ---- S2: issue g1(h1(t)); fh2 frags; L2 h2-half; head(t-1) covers g1 flight ----
    if (t > 0) ISSUE_G8(&h1r[ur*512 + uc*16], g1a, g1b, g1c, g1d);
    bf16x8 fh2[8];
#pragma unroll
    for (int j = 0; j < 8; ++j)
      fh2[j] = *(bf16x8*)((char*)inH2 + ln*512 + ((j*64 + lk*16) ^ ((ln&7)<<4)));
    f32x4 acc2 = {0.f,0.f,0.f,0.f};
#pragma unroll
    for (int j = 0; j < 8; ++j)
      acc2 = __builtin_amdgcn_mfma_f32_16x16x32_bf16(w2f[8+j], fh2[j], acc2, 0, 0, 0);

    float outv = 0.f; bool dow = false; size_t oaddr = 0;
    if (t > 0){
      f32x4 acc3a = {0,0,0,0}, acc3b = {0,0,0,0};
#pragma unroll
      for (int j = 0; j < 8; ++j){
        acc3a = __builtin_amdgcn_mfma_f32_16x16x32_bf16(w3f[0][j], fh2[j], acc3a, 0, 0, 0);
        acc3b = __builtin_amdgcn_mfma_f32_16x16x32_bf16(w3f[1][j], fh2[j], acc3b, 0, 0, 0);
      }
      if (ln == sb){
#pragma unroll
        for (int r4 = 0; r4 < 4; ++r4){
          int d0 = wv*32 + lk*4 + r4;
          h3p[d0] = acc3a[r4]; h3p[d0+16] = acc3b[r4];
        }
      }
      if (ln == sb + 8){
#pragma unroll
        for (int r4 = 0; r4 < 4; ++r4){
          int d0 = wv*32 + lk*4 + r4;
          h3q[d0] = acc3a[r4]; h3q[d0+16] = acc3b[r4];
        }
      }
      BARRIER();
      if (tid < 128) h3row[tid] = fmaxf(h3p[tid] + h3q[tid] + b3L[tid], 0.0f);
      BARRIER();
      if (wv == 0){
        const int l = tid, c = l >> 2, kq = l & 3;
        float p = 0.f;
        if (c < 10){
          const float* wr = &W4L[c*134 + kq*33];
          const float* hr = &h3row[kq*32];
#pragma unroll
          for (int k = 0; k < 32; ++k) p += wr[k]*hr[k];
        }
        p += __shfl_xor(p, 1, 4);
        p += __shfl_xor(p, 2, 4);
        if (c < 10 && kq == 0) ytmp[c] = p + b4L[c];
        asm volatile("s_waitcnt lgkmcnt(0)" ::: "memory");
        float yv = (l < 10) ? ytmp[l] : -INFINITY;
        float mx = yv;
#pragma unroll
        for (int off = 1; off < 16; off <<= 1)
          mx = fmaxf(mx, __shfl_xor(mx, off, 16));
        float ex = (l < 10) ? expf(yv - mx) : 0.0f;
        float sm = ex;
#pragma unroll
        for (int off = 1; off < 16; off <<= 1)
          sm += __shfl_xor(sm, off, 16);
        if (l < 10){
          outv = yv - (mx + logf(sm));
          dow = true;
          oaddr = ((size_t)(gp*GR + sb)*NT + (t-1))*NC + l;
        }
      }
    }

    // ---- S3: consume h1(t); stage x(t+1) (full drain — g1 + ancient x only) ----
    WAITV4(0, g1a, g1b, g1c, g1d);
    {
      bf16x8 hv, lv;
      if (!chk_unpack(g1a, g1b, g1c, g1d, (unsigned)(t+1), hv, lv))
        gather8(&h1r[ur*512 + uc*16], (unsigned)(t+1), hv, lv);
      *(bf16x8*)((char*)inH1 + ur*512     + ((uc*16) ^ ((ur&7)<<4))) = hv;
      *(bf16x8*)((char*)inH1 + (ur+8)*512 + ((uc*16) ^ ((ur&7)<<4))) = lv;
    }
    if (haveX && xr < 8){
      bf16x8 hv, lv;
      split8(xa, xb, hv, lv);
      *(bf16x8*)((char*)inX + xr*256     + ((xf*16) ^ ((xr&7)<<4))) = hv;
      *(bf16x8*)((char*)inX + (xr+8)*256 + ((xf*16) ^ ((xr&7)<<4))) = lv;
    }
    BARRIER();

    // ---- S4: L2 h1-half -> gate -> post h2(t) ----
    bf16x8 fh1[8];
#pragma unroll
    for (int j = 0; j < 8; ++j)
      fh1[j] = *(bf16x8*)((char*)inH1 + ln*512 + ((j*64 + lk*16) ^ ((ln&7)<<4)));
#pragma unroll
    for (int j = 0; j < 8; ++j)
      acc2 = __builtin_amdgcn_mfma_f32_16x16x32_bf16(w2f[j], fh1[j], acc2, 0, 0, 0);
#pragma unroll
    for (int r4 = 0; r4 < 4; ++r4)
      aldsB[wv*16 + lk*4 + r4][ln] = acc2[r4];
    BARRIER();
    {
      float az = aldsB[uc][ur]    + aldsB[uc][ur+8]    + b2s[uc];
      float ac = aldsB[32+uc][ur] + aldsB[32+uc][ur+8] + b2s[32+uc];
      float z  = 0.5f*(az/(1.0f+fabsf(az)) + 1.0f);
      float cd = ac/(1.0f+fabsf(ac));
      float hn = z*h2own[uc][ur] + (1.0f - z)*cd;
      h2own[uc][ur] = hn;
      short hb = f2bf(hn), lb = f2bf(hn - bf2f(hb));
      st_msg(&h2w[ur*512 + (rz + uc)*2], hb, lb, (unsigned)(t+1));
    }

    // ---- S5: L1(t+1) -> gate -> post h1(t+1) (next iter gathers it — full slack) ----
    if (haveX){
      f32x4 acc1 = {0.f,0.f,0.f,0.f};
#pragma unroll
      for (int j = 0; j < 4; ++j){
        bf16x8 fx = *(bf16x8*)((char*)inX + ln*256 + ((j*64 + lk*16) ^ ((ln&7)<<4)));
        acc1 = __builtin_amdgcn_mfma_f32_16x16x32_bf16(w1f[j], fx, acc1, 0, 0, 0);
      }
#pragma unroll
      for (int j = 0; j < 8; ++j)
        acc1 = __builtin_amdgcn_mfma_f32_16x16x32_bf16(w1f[4+j], fh1[j], acc1, 0, 0, 0);
#pragma unroll
      for (int r4 = 0; r4 < 4; ++r4)
        aldsA[wv*16 + lk*4 + r4][ln] = acc1[r4];
      BARRIER();
      float az = aldsA[uc][ur]    + aldsA[uc][ur+8]    + b1s[uc];
      float ac = aldsA[32+uc][ur] + aldsA[32+uc][ur+8] + b1s[32+uc];
      float z  = 0.5f*(az/(1.0f+fabsf(az)) + 1.0f);
      float cd = ac/(1.0f+fabsf(ac));
      float hn = z*h1own[uc][ur] + (1.0f - z)*cd;
      h1own[uc][ur] = hn;
      short hb = f2bf(hn), lb = f2bf(hn - bf2f(hb));
      st_msg(&h1w[ur*512 + (rz + uc)*2], hb, lb, (unsigned)(t+2));
    }

    // ---- S6: deferred out store; issue next gathers + x(t+2) ----
    if (dow) outg[oaddr] = outv;   // wave0 only; stays OLDER than next iter's waited loads
    if (t < NT-1) ISSUE_G8(&h2w[ur*512 + uc*16], g2a, g2b, g2c, g2d);
    if (t + 2 < NT){
      const float* px = xg + ((size_t)(gp*GR + xrl)*NT + (t+2))*FB + xf*8;
      ISSUE_X2(px, xa, xb);
    }
  }

  // ---- epilogue: gather h2(NT-1) (epoch NT), head(NT-1) ----
  {
    unsigned* h2e = h2buf + (unsigned)((NT-1) & 1)*131072u + (unsigned)(gp*GR)*512u;
    bf16x8 hv, lv;
    gather8(&h2e[ur*512 + uc*16], (unsigned)NT, hv, lv);
    *(bf16x8*)((char*)inH2 + ur*512     + ((uc*16) ^ ((ur&7)<<4))) = hv;
    *(bf16x8*)((char*)inH2 + (ur+8)*512 + ((uc*16) ^ ((ur&7)<<4))) = lv;
  }
  BARRIER();
  {
    bf16x8 fh2[8];
#pragma unroll
    for (int j = 0; j < 8; ++j)
      fh2[j] = *(bf16x8*)((char*)inH2 + ln*512 + ((j*64 + lk*16) ^ ((ln&7)<<4)));
    f32x4 acc3a = {0,0,0,0}, acc3b = {0,0,0,0};
#pragma unroll
    for (int j = 0; j < 8; ++j){
      acc3a = __builtin_amdgcn_mfma_f32_16x16x32_bf16(w3f[0][j], fh2[j], acc3a, 0, 0, 0);
      acc3b = __builtin_amdgcn_mfma_f32_16x16x32_bf16(w3f[1][j], fh2[j], acc3b, 0, 0, 0);
    }
    if (ln == sb){
#pragma unroll
      for (int r4 = 0; r4 < 4; ++r4){
        int d0 = wv*32 + lk*4 + r4;
        h3p[d0] = acc3a[r4]; h3p[d0+16] = acc3b[r4];
      }
    }
    if (ln == sb + 8){
#pragma unroll
      for (int r4 = 0; r4 < 4; ++r4){
        int d0 = wv*32 + lk*4 + r4;
        h3q[d0] = acc3a[r4]; h3q[d0+16] = acc3b[r4];
      }
    }
    BARRIER();
    if (tid < 128) h3row[tid] = fmaxf(h3p[tid] + h3q[tid] + b3L[tid], 0.0f);
    BARRIER();
    if (wv == 0){
      const int l = tid, c = l >> 2, kq = l & 3;
      float p = 0.f;
      if (c < 10){
        const float* wr = &W4L[c*134 + kq*33];
        const float* hr = &h3row[kq*32];
#pragma unroll
        for (int k = 0; k < 32; ++k) p += wr[k]*hr[k];
      }
      p += __shfl_xor(p, 1, 4);
      p += __shfl_xor(p, 2, 4);
      if (c < 10 && kq == 0) ytmp[c] = p + b4L[c];
      asm volatile("s_waitcnt lgkmcnt(0)" ::: "memory");
      float yv = (l < 10) ? ytmp[l] : -INFINITY;
      float mx = yv;
#pragma unroll
      for (int off = 1; off < 16; off <<= 1)
        mx = fmaxf(mx, __shfl_xor(mx, off, 16));
      float ex = (l < 10) ? expf(yv - mx) : 0.0f;
      float sm = ex;
#pragma unroll
      for (int off = 1; off < 16; off <<= 1)
        sm += __shfl_xor(sm, off, 16);
      if (l < 10)
        outg[((size_t)(gp*GR + sb)*NT + (NT-1))*NC + l] = yv - (mx + logf(sm));
    }
  }
}

extern "C" void kernel_launch(void* const* d_in, const int* in_sizes, int n_in,
                              void* d_out, int out_size, void* d_ws, size_t ws_size,
                              hipStream_t stream) {
  const float* xg  = (const float*)d_in[0];
  const float* h1i = (const float*)d_in[1];
  const float* h2i = (const float*)d_in[2];
  const float* W1  = (const float*)d_in[3];
  const float* b1  = (const float*)d_in[4];
  const float* W2  = (const float*)d_in[5];
  const float* b2  = (const float*)d_in[6];
  const float* W3  = (const float*)d_in[7];
  const float* b3  = (const float*)d_in[8];
  const float* W4  = (const float*)d_in[9];
  const float* b4  = (const float*)d_in[10];
  float* out = (float*)d_out;
  float* ws  = (float*)d_ws;

  // clear all message epochs (stale epochs from a previous replay would falsely validate)
  hipMemsetAsync(d_ws, 0, 2u * 1024u * 1024u, stream);

  egru_persistent<<<dim3(256), dim3(256), 0, stream>>>(
      xg, h1i, h2i, W1, b1, W2, b2, W3, b3, W4, b4, out, ws);
}

// Round 14
// 2015.060 us; speedup vs baseline: 1.1016x; 1.1016x over previous
//
#include <hip/hip_runtime.h>

#define NT 512   // timesteps
#define FB 128   // feature bins
#define HD 256   // L1 == L2 hidden
#define NC 10

typedef __attribute__((ext_vector_type(8))) short bf16x8;
typedef __attribute__((ext_vector_type(4))) float f32x4;
typedef __attribute__((ext_vector_type(4))) unsigned u32x4;

static __device__ __forceinline__ short f2bf(float f){
  union { float f; unsigned u; } v; v.f = f;
  return (short)((v.u + 0x7fffu + ((v.u >> 16) & 1u)) >> 16);  // RNE
}
static __device__ __forceinline__ float bf2f(short h){
  union { unsigned u; float f; } v; v.u = ((unsigned)(unsigned short)h) << 16;
  return v.f;
}
static __device__ __forceinline__ float quantw(float w){
  return fminf(fmaxf(rintf(w * 8.0f) * 0.125f, -1.0f), 1.0f);  // exact in bf16
}
static __device__ __forceinline__ bf16x8 loadqw8(const float* __restrict__ p){
  bf16x8 v;
#pragma unroll
  for (int j = 0; j < 8; ++j) v[j] = f2bf(quantw(p[j]));
  return v;
}
static __device__ __forceinline__ void split8(f32x4 a, f32x4 b, bf16x8& hi, bf16x8& lo){
  float v0[4] = {a[0],a[1],a[2],a[3]}, v1[4] = {b[0],b[1],b[2],b[3]};
#pragma unroll
  for (int j = 0; j < 4; ++j){
    short h = f2bf(v0[j]); hi[j] = h; lo[j] = f2bf(v0[j] - bf2f(h));
  }
#pragma unroll
  for (int j = 0; j < 4; ++j){
    short h = f2bf(v1[j]); hi[4+j] = h; lo[4+j] = f2bf(v1[j] - bf2f(h));
  }
}

// ---- epoch-in-band messaging over sc1 (R9-proven) ----
static __device__ __forceinline__ void st_msg(unsigned* p, short hb, short lb, unsigned ep){
  __attribute__((ext_vector_type(2))) unsigned w;
  w[0] = (((unsigned)(unsigned short)hb) << 16) | ep;
  w[1] = (((unsigned)(unsigned short)lb) << 16) | ep;
  asm volatile("global_store_dwordx2 %0, %1, off sc1" :: "v"(p), "v"(w) : "memory");
}
static __device__ __forceinline__ void gather8(const unsigned* p, unsigned ep, bf16x8& hv, bf16x8& lv){
  u32x4 a, b, c, d;
  for (;;){
    asm volatile("global_load_dwordx4 %0, %4, off sc1\n\t"
                 "global_load_dwordx4 %1, %4, off offset:16 sc1\n\t"
                 "global_load_dwordx4 %2, %4, off offset:32 sc1\n\t"
                 "global_load_dwordx4 %3, %4, off offset:48 sc1\n\t"
                 "s_waitcnt vmcnt(0)"
                 : "=&v"(a), "=&v"(b), "=&v"(c), "=&v"(d) : "v"(p) : "memory");
    unsigned m = (a[0]^ep)|(a[1]^ep)|(a[2]^ep)|(a[3]^ep)
               | (b[0]^ep)|(b[1]^ep)|(b[2]^ep)|(b[3]^ep)
               | (c[0]^ep)|(c[1]^ep)|(c[2]^ep)|(c[3]^ep)
               | (d[0]^ep)|(d[1]^ep)|(d[2]^ep)|(d[3]^ep);
    if ((m & 0xffffu) == 0u) break;
  }
  hv[0]=(short)(a[0]>>16); lv[0]=(short)(a[1]>>16);
  hv[1]=(short)(a[2]>>16); lv[1]=(short)(a[3]>>16);
  hv[2]=(short)(b[0]>>16); lv[2]=(short)(b[1]>>16);
  hv[3]=(short)(b[2]>>16); lv[3]=(short)(b[3]>>16);
  hv[4]=(short)(c[0]>>16); lv[4]=(short)(c[1]>>16);
  hv[5]=(short)(c[2]>>16); lv[5]=(short)(c[3]>>16);
  hv[6]=(short)(d[0]>>16); lv[6]=(short)(d[1]>>16);
  hv[7]=(short)(d[2]>>16); lv[7]=(short)(d[3]>>16);
}
static __device__ __forceinline__ bool chk_unpack(u32x4 a, u32x4 b, u32x4 c, u32x4 d,
                                                  unsigned ep, bf16x8& hv, bf16x8& lv){
  unsigned m = (a[0]^ep)|(a[1]^ep)|(a[2]^ep)|(a[3]^ep)
             | (b[0]^ep)|(b[1]^ep)|(b[2]^ep)|(b[3]^ep)
             | (c[0]^ep)|(c[1]^ep)|(c[2]^ep)|(c[3]^ep)
             | (d[0]^ep)|(d[1]^ep)|(d[2]^ep)|(d[3]^ep);
  if ((m & 0xffffu) != 0u) return false;
  hv[0]=(short)(a[0]>>16); lv[0]=(short)(a[1]>>16);
  hv[1]=(short)(a[2]>>16); lv[1]=(short)(a[3]>>16);
  hv[2]=(short)(b[0]>>16); lv[2]=(short)(b[1]>>16);
  hv[3]=(short)(b[2]>>16); lv[3]=(short)(b[3]>>16);
  hv[4]=(short)(c[0]>>16); lv[4]=(short)(c[1]>>16);
  hv[5]=(short)(c[2]>>16); lv[5]=(short)(c[3]>>16);
  hv[6]=(short)(d[0]>>16); lv[6]=(short)(d[1]>>16);
  hv[7]=(short)(d[2]>>16); lv[7]=(short)(d[3]>>16);
  return true;
}

#define ISSUE_G8(P,A,B,C,D) \
  asm volatile("global_load_dwordx4 %0, %4, off sc1\n\t" \
               "global_load_dwordx4 %1, %4, off offset:16 sc1\n\t" \
               "global_load_dwordx4 %2, %4, off offset:32 sc1\n\t" \
               "global_load_dwordx4 %3, %4, off offset:48 sc1" \
               : "=&v"(A),"=&v"(B),"=&v"(C),"=&v"(D) : "v"(P) : "memory")
#define ISSUE_X2(P,A,B) \
  asm volatile("global_load_dwordx4 %0, %2, off\n\t" \
               "global_load_dwordx4 %1, %2, off offset:16" \
               : "=&v"(A),"=&v"(B) : "v"(P) : "memory")
#define WAITV4(N,A,B,C,D) do{ \
  asm volatile("s_waitcnt vmcnt(" #N ")" : "+v"(A),"+v"(B),"+v"(C),"+v"(D) :: "memory"); \
  __builtin_amdgcn_sched_barrier(0); }while(0)
#define BARRIER() do{ asm volatile("s_waitcnt lgkmcnt(0)" ::: "memory"); \
  __builtin_amdgcn_s_barrier(); asm volatile("" ::: "memory"); }while(0)

// 256 blocks x 256 threads, 1 block/CU. gp = bid&31, sb = bid>>5 (same-XCD peers).
// DUAL recurrences per block: rec A = batch rows gp*4..+3, rec B = 128+gp*4..+3.
// Shared weight frags; merged gates/gathers (A on tid<128, B on tid>=128); per-rec
// MFMA phases interleaved so each exchange wait is covered by the other rec's work.
__global__ __launch_bounds__(256, 1)
void egru_persistent(const float* __restrict__ xg,
                     const float* __restrict__ h1ig, const float* __restrict__ h2ig,
                     const float* __restrict__ W1g, const float* __restrict__ b1g,
                     const float* __restrict__ W2g, const float* __restrict__ b2g,
                     const float* __restrict__ W3g, const float* __restrict__ b3g,
                     const float* __restrict__ W4g, const float* __restrict__ b4g,
                     float* __restrict__ outg, float* __restrict__ wsf)
{
  const int tid = threadIdx.x;
  const int gp  = blockIdx.x & 31;
  const int sb  = blockIdx.x >> 5;
  const int wv  = tid >> 6;
  const int ln  = tid & 15;
  const int lk  = (tid >> 4) & 3;
  const int rz  = sb * 32;

  const int rc  = tid >> 7;          // 0 = rec A, 1 = rec B
  const int th  = tid & 127;
  const int r_  = th >> 5;           // row 0..3 within rec
  const int d_  = th & 31;           // dim (gate) / dim-chunk (gather)
  const int grow = rc*128 + gp*4 + r_;          // global batch row (gate/gather)
  const int xr  = th >> 4, xf = th & 15;        // x staging; valid xr<4
  const int xrow = rc*128 + gp*4 + (xr & 3);    // clamped x row (uniform loads)

  __shared__ __align__(16) short inX [2*16*128];  // per-rec x tile; 256 B/row
  __shared__ __align__(16) short inH1[2*16*256];  // per-rec h1 tile; 512 B/row
  __shared__ __align__(16) short inH2[2*16*256];  // per-rec h2 tile
  __shared__ float alds1[2][64][17];
  __shared__ float alds2[2][64][17];
  __shared__ float h1own[2][32][4];
  __shared__ float h2own[2][32][4];
  __shared__ float h3p[128], h3q[128], h3row[128];
  __shared__ float ytmp[16];
  __shared__ float W4L[1344];                     // skewed: c*134 + (k>>5)*33 + (k&31)
  __shared__ float b1s[64], b2s[64], b3L[128], b4L[10];

  unsigned* h1buf = reinterpret_cast<unsigned*>(wsf);
  unsigned* h2buf = h1buf + 262144;

  bf16x8 w1f[12], w2f[16], w3f[2][8];
  {
    const int arow = (wv < 2) ? (rz + wv*16 + ln) : (256 + rz + (wv-2)*16 + ln);
#pragma unroll
    for (int ks = 0; ks < 12; ++ks) w1f[ks] = loadqw8(W1g + arow*384 + ks*32 + lk*8);
#pragma unroll
    for (int ks = 0; ks < 16; ++ks) w2f[ks] = loadqw8(W2g + arow*512 + ks*32 + lk*8);
#pragma unroll
    for (int tl = 0; tl < 2; ++tl)
#pragma unroll
      for (int ks = 0; ks < 8; ++ks)
        w3f[tl][ks] = loadqw8(W3g + (wv*32 + tl*16 + ln)*256 + ks*32 + lk*8);
  }

  if (tid < 64){
    int grw = (tid < 32) ? (rz + tid) : (256 + rz + (tid - 32));
    b1s[tid] = b1g[grw];
    b2s[tid] = b2g[grw];
  }
  if (tid < 128) b3L[tid] = b3g[tid];
  if (tid < 10)  b4L[tid] = b4g[tid];
  for (int i = tid; i < 1280; i += 256){
    int c = i >> 7, k = i & 127;
    W4L[c*134 + (k>>5)*33 + (k&31)] = quantw(W4g[i]);
  }

  // zero all B-tiles (rows 4-7 / 12-15 must stay zero forever)
  for (int i = tid; i < 2048; i += 256) ((int*)inX )[i] = 0;
  for (int i = tid; i < 4096; i += 256) ((int*)inH1)[i] = 0;
  for (int i = tid; i < 4096; i += 256) ((int*)inH2)[i] = 0;
  __syncthreads();

  {
    bf16x8 hv, lv;
    const float* p1 = h1ig + (size_t)grow*HD + d_*8;
    split8(*(const f32x4*)p1, *(const f32x4*)(p1+4), hv, lv);
    char* bH1 = (char*)inH1 + rc*8192;
    *(bf16x8*)(bH1 + r_*512     + ((d_*16) ^ ((r_&7)<<4))) = hv;
    *(bf16x8*)(bH1 + (r_+8)*512 + ((d_*16) ^ ((r_&7)<<4))) = lv;
    const float* p2 = h2ig + (size_t)grow*HD + d_*8;
    split8(*(const f32x4*)p2, *(const f32x4*)(p2+4), hv, lv);
    char* bH2 = (char*)inH2 + rc*8192;
    *(bf16x8*)(bH2 + r_*512     + ((d_*16) ^ ((r_&7)<<4))) = hv;
    *(bf16x8*)(bH2 + (r_+8)*512 + ((d_*16) ^ ((r_&7)<<4))) = lv;
    h1own[rc][d_][r_] = h1ig[(size_t)grow*HD + rz + d_];
    h2own[rc][d_][r_] = h2ig[(size_t)grow*HD + rz + d_];
  }
  if (xr < 4){
    const float* px = xg + ((size_t)(rc*128 + gp*4 + xr)*NT + 0)*FB + xf*8;
    bf16x8 hv, lv;
    split8(*(const f32x4*)px, *(const f32x4*)(px+4), hv, lv);
    char* bX = (char*)inX + rc*4096;
    *(bf16x8*)(bX + xr*256     + ((xf*16) ^ (xr<<4))) = hv;
    *(bf16x8*)(bX + (xr+8)*256 + ((xf*16) ^ (xr<<4))) = lv;
  }
  __syncthreads();

  // ---- prologue: L1(0) for both recs ----
  f32x4 accA = {0.f,0.f,0.f,0.f}, accB = {0.f,0.f,0.f,0.f};
#pragma unroll
  for (int j = 0; j < 4; ++j){
    bf16x8 fxA = *(bf16x8*)((char*)inX + 0    + ln*256 + ((j*64 + lk*16) ^ ((ln&7)<<4)));
    bf16x8 fxB = *(bf16x8*)((char*)inX + 4096 + ln*256 + ((j*64 + lk*16) ^ ((ln&7)<<4)));
    accA = __builtin_amdgcn_mfma_f32_16x16x32_bf16(w1f[j], fxA, accA, 0, 0, 0);
    accB = __builtin_amdgcn_mfma_f32_16x16x32_bf16(w1f[j], fxB, accB, 0, 0, 0);
  }
#pragma unroll
  for (int j = 0; j < 8; ++j){
    bf16x8 fhA = *(bf16x8*)((char*)inH1 + 0    + ln*512 + ((j*64 + lk*16) ^ ((ln&7)<<4)));
    bf16x8 fhB = *(bf16x8*)((char*)inH1 + 8192 + ln*512 + ((j*64 + lk*16) ^ ((ln&7)<<4)));
    accA = __builtin_amdgcn_mfma_f32_16x16x32_bf16(w1f[4+j], fhA, accA, 0, 0, 0);
    accB = __builtin_amdgcn_mfma_f32_16x16x32_bf16(w1f[4+j], fhB, accB, 0, 0, 0);
  }
  f32x4 xa = {0,0,0,0}, xb = {0,0,0,0};
  ISSUE_X2(xg + ((size_t)xrow*NT + 1)*FB + xf*8, xa, xb);
  u32x4 g1a, g1b, g1c, g1d, g2a, g2b, g2c, g2d;

  for (int t = 0; t < NT; ++t){
    unsigned* h1s = h1buf + (unsigned)(t & 1)*131072u;       // h1(t) slot (write+read)
    unsigned* h2s = h2buf + (unsigned)(t & 1)*131072u;       // h2(t) write slot
    unsigned* h2r = h2buf + (unsigned)((t + 1) & 1)*131072u; // h2(t-1) read slot
    const bool notlast = (t + 1) < NT;

    // ---- S1: gates h1 (merged A/B) -> post stH1 ----
#pragma unroll
    for (int r4 = 0; r4 < 4; ++r4){
      alds1[0][wv*16 + lk*4 + r4][ln] = accA[r4];
      alds1[1][wv*16 + lk*4 + r4][ln] = accB[r4];
    }
    BARRIER();
    {
      float az = alds1[rc][d_][r_]    + alds1[rc][d_][r_+8]    + b1s[d_];
      float ac = alds1[rc][32+d_][r_] + alds1[rc][32+d_][r_+8] + b1s[32+d_];
      float z  = 0.5f*(az/(1.0f+fabsf(az)) + 1.0f);
      float cd = ac/(1.0f+fabsf(ac));
      float hn = z*h1own[rc][d_][r_] + (1.0f - z)*cd;
      h1own[rc][d_][r_] = hn;
      short hb = f2bf(hn), lb = f2bf(hn - bf2f(hb));
      st_msg(h1s + (unsigned)grow*512u + (rz + d_)*2, hb, lb, (unsigned)(t+1));
    }

    // ---- S2: consume h2(t-1) (merged; posted prev S7, gathered prev S9) ----
    if (t > 0){
      WAITV4(3, g2a, g2b, g2c, g2d);   // newer-than-g2: x*2 + [out] + stH1 -> 3 uniform-safe
      bf16x8 hv, lv;
      if (!chk_unpack(g2a, g2b, g2c, g2d, (unsigned)t, hv, lv))
        gather8(h2r + (unsigned)grow*512u + d_*16, (unsigned)t, hv, lv);
      char* bH2 = (char*)inH2 + rc*8192;
      *(bf16x8*)(bH2 + r_*512     + ((d_*16) ^ ((r_&7)<<4))) = hv;
      *(bf16x8*)(bH2 + (r_+8)*512 + ((d_*16) ^ ((r_&7)<<4))) = lv;
    }
    BARRIER();

    // ---- S3: fh2 both recs; L2 h2-half A then B ----
    bf16x8 fh2A[8], fh2B[8];
#pragma unroll
    for (int j = 0; j < 8; ++j){
      fh2A[j] = *(bf16x8*)((char*)inH2 + 0    + ln*512 + ((j*64 + lk*16) ^ ((ln&7)<<4)));
      fh2B[j] = *(bf16x8*)((char*)inH2 + 8192 + ln*512 + ((j*64 + lk*16) ^ ((ln&7)<<4)));
    }
    f32x4 ac2A = {0.f,0.f,0.f,0.f}, ac2B = {0.f,0.f,0.f,0.f};
#pragma unroll
    for (int j = 0; j < 8; ++j)
      ac2A = __builtin_amdgcn_mfma_f32_16x16x32_bf16(w2f[8+j], fh2A[j], ac2A, 0, 0, 0);
#pragma unroll
    for (int j = 0; j < 8; ++j)
      ac2B = __builtin_amdgcn_mfma_f32_16x16x32_bf16(w2f[8+j], fh2B[j], ac2B, 0, 0, 0);

    // ---- S4: issue g1 (h1(t), posted S1 ~0.4us ago; consumed S6 after head) ----
    ISSUE_G8(h1s + (unsigned)grow*512u + d_*16, g1a, g1b, g1c, g1d);

    // ---- S5: head(t-1) — ONE head per block (sb<4 -> rec A col sb; else rec B) ----
    float outv = 0.f; bool dow = false; size_t oaddr = 0;
    if (t > 0){
      const int hcol = sb & 3;
      f32x4 a3a = {0,0,0,0}, a3b = {0,0,0,0};
      if (sb < 4){
#pragma unroll
        for (int j = 0; j < 8; ++j){
          a3a = __builtin_amdgcn_mfma_f32_16x16x32_bf16(w3f[0][j], fh2A[j], a3a, 0, 0, 0);
          a3b = __builtin_amdgcn_mfma_f32_16x16x32_bf16(w3f[1][j], fh2A[j], a3b, 0, 0, 0);
        }
      } else {
#pragma unroll
        for (int j = 0; j < 8; ++j){
          a3a = __builtin_amdgcn_mfma_f32_16x16x32_bf16(w3f[0][j], fh2B[j], a3a, 0, 0, 0);
          a3b = __builtin_amdgcn_mfma_f32_16x16x32_bf16(w3f[1][j], fh2B[j], a3b, 0, 0, 0);
        }
      }
      if (ln == hcol){
#pragma unroll
        for (int r4 = 0; r4 < 4; ++r4){
          int d0 = wv*32 + lk*4 + r4;
          h3p[d0] = a3a[r4]; h3p[d0+16] = a3b[r4];
        }
      }
      if (ln == hcol + 8){
#pragma unroll
        for (int r4 = 0; r4 < 4; ++r4){
          int d0 = wv*32 + lk*4 + r4;
          h3q[d0] = a3a[r4]; h3q[d0+16] = a3b[r4];
        }
      }
      BARRIER();
      if (tid < 128) h3row[tid] = fmaxf(h3p[tid] + h3q[tid] + b3L[tid], 0.0f);
      BARRIER();
      if (wv == 0){
        const int l = tid, c = l >> 2, kq = l & 3;
        float p = 0.f;
        if (c < 10){
          const float* wr = &W4L[c*134 + kq*33];
          const float* hr = &h3row[kq*32];
#pragma unroll
          for (int k = 0; k < 32; ++k) p += wr[k]*hr[k];
        }
        p += __shfl_xor(p, 1, 4);
        p += __shfl_xor(p, 2, 4);
        if (c < 10 && kq == 0) ytmp[c] = p + b4L[c];
        asm volatile("s_waitcnt lgkmcnt(0)" ::: "memory");
        float yv = (l < 10) ? ytmp[l] : -INFINITY;
        float mx = yv;
#pragma unroll
        for (int off = 1; off < 16; off <<= 1)
          mx = fmaxf(mx, __shfl_xor(mx, off, 16));
        float ex = (l < 10) ? expf(yv - mx) : 0.0f;
        float sm = ex;
#pragma unroll
        for (int off = 1; off < 16; off <<= 1)
          sm += __shfl_xor(sm, off, 16);
        if (l < 10){
          int orow = (sb < 4) ? (gp*4 + sb) : (128 + gp*4 + (sb - 4));
          outv = yv - (mx + logf(sm));
          dow = true;
          oaddr = ((size_t)orow*NT + (t-1))*NC + l;
        }
      }
    }

    // ---- S6: consume h1(t) + x(t+1) (full drain; g1 newest) ----
    WAITV4(0, g1a, g1b, g1c, g1d);
    {
      bf16x8 hv, lv;
      if (!chk_unpack(g1a, g1b, g1c, g1d, (unsigned)(t+1), hv, lv))
        gather8(h1s + (unsigned)grow*512u + d_*16, (unsigned)(t+1), hv, lv);
      char* bH1 = (char*)inH1 + rc*8192;
      *(bf16x8*)(bH1 + r_*512     + ((d_*16) ^ ((r_&7)<<4))) = hv;
      *(bf16x8*)(bH1 + (r_+8)*512 + ((d_*16) ^ ((r_&7)<<4))) = lv;
    }
    if (notlast && xr < 4){
      bf16x8 hv, lv;
      split8(xa, xb, hv, lv);
      char* bX = (char*)inX + rc*4096;
      *(bf16x8*)(bX + xr*256     + ((xf*16) ^ (xr<<4))) = hv;
      *(bf16x8*)(bX + (xr+8)*256 + ((xf*16) ^ (xr<<4))) = lv;
    }
    BARRIER();

    // ---- S7: fh1 both recs; finish L2 (h1-half); gates h2 merged -> post stH2 ----
    bf16x8 fh1A[8], fh1B[8];
#pragma unroll
    for (int j = 0; j < 8; ++j){
      fh1A[j] = *(bf16x8*)((char*)inH1 + 0    + ln*512 + ((j*64 + lk*16) ^ ((ln&7)<<4)));
      fh1B[j] = *(bf16x8*)((char*)inH1 + 8192 + ln*512 + ((j*64 + lk*16) ^ ((ln&7)<<4)));
    }
#pragma unroll
    for (int j = 0; j < 8; ++j)
      ac2A = __builtin_amdgcn_mfma_f32_16x16x32_bf16(w2f[j], fh1A[j], ac2A, 0, 0, 0);
#pragma unroll
    for (int j = 0; j < 8; ++j)
      ac2B = __builtin_amdgcn_mfma_f32_16x16x32_bf16(w2f[j], fh1B[j], ac2B, 0, 0, 0);
#pragma unroll
    for (int r4 = 0; r4 < 4; ++r4){
      alds2[0][wv*16 + lk*4 + r4][ln] = ac2A[r4];
      alds2[1][wv*16 + lk*4 + r4][ln] = ac2B[r4];
    }
    BARRIER();
    {
      float az = alds2[rc][d_][r_]    + alds2[rc][d_][r_+8]    + b2s[d_];
      float ac = alds2[rc][32+d_][r_] + alds2[rc][32+d_][r_+8] + b2s[32+d_];
      float z  = 0.5f*(az/(1.0f+fabsf(az)) + 1.0f);
      float cd = ac/(1.0f+fabsf(ac));
      float hn = z*h2own[rc][d_][r_] + (1.0f - z)*cd;
      h2own[rc][d_][r_] = hn;
      short hb = f2bf(hn), lb = f2bf(hn - bf2f(hb));
      st_msg(h2s + (unsigned)grow*512u + (rz + d_)*2, hb, lb, (unsigned)(t+1));
    }

    // ---- S8: L1(t+1) both recs (covers stH2 ack + fills before next wait) ----
    if (notlast){
      f32x4 nA = {0.f,0.f,0.f,0.f}, nB = {0.f,0.f,0.f,0.f};
#pragma unroll
      for (int j = 0; j < 4; ++j){
        bf16x8 fxA = *(bf16x8*)((char*)inX + 0    + ln*256 + ((j*64 + lk*16) ^ ((ln&7)<<4)));
        bf16x8 fxB = *(bf16x8*)((char*)inX + 4096 + ln*256 + ((j*64 + lk*16) ^ ((ln&7)<<4)));
        nA = __builtin_amdgcn_mfma_f32_16x16x32_bf16(w1f[j], fxA, nA, 0, 0, 0);
        nB = __builtin_amdgcn_mfma_f32_16x16x32_bf16(w1f[j], fxB, nB, 0, 0, 0);
      }
#pragma unroll
      for (int j = 0; j < 8; ++j){
        nA = __builtin_amdgcn_mfma_f32_16x16x32_bf16(w1f[4+j], fh1A[j], nA, 0, 0, 0);
        nB = __builtin_amdgcn_mfma_f32_16x16x32_bf16(w1f[4+j], fh1B[j], nB, 0, 0, 0);
      }
      accA = nA; accB = nB;
    }

    // ---- S9: issue g2 (h2(t)); issue x(t+2, clamped); deferred out last ----
    ISSUE_G8(h2s + (unsigned)grow*512u + d_*16, g2a, g2b, g2c, g2d);
    {
      int xt = (t + 2 < NT) ? (t + 2) : (NT - 1);
      ISSUE_X2(xg + ((size_t)xrow*NT + xt)*FB + xf*8, xa, xb);
    }
    if (dow) outg[oaddr] = outv;
  }

  // ---- epilogue: consume h2(NT-1) (epoch NT), head(NT-1) ----
  {
    unsigned* h2e = h2buf + (unsigned)((NT-1) & 1)*131072u;
    WAITV4(0, g2a, g2b, g2c, g2d);
    bf16x8 hv, lv;
    if (!chk_unpack(g2a, g2b, g2c, g2d, (unsigned)NT, hv, lv))
      gather8(h2e + (unsigned)grow*512u + d_*16, (unsigned)NT, hv, lv);
    char* bH2 = (char*)inH2 + rc*8192;
    *(bf16x8*)(bH2 + r_*512     + ((d_*16) ^ ((r_&7)<<4))) = hv;
    *(bf16x8*)(bH2 + (r_+8)*512 + ((d_*16) ^ ((r_&7)<<4))) = lv;
  }
  BARRIER();
  {
    const int hcol = sb & 3;
    const int hoff = (sb < 4) ? 0 : 8192;
    bf16x8 fhh[8];
#pragma unroll
    for (int j = 0; j < 8; ++j)
      fhh[j] = *(bf16x8*)((char*)inH2 + hoff + ln*512 + ((j*64 + lk*16) ^ ((ln&7)<<4)));
    f32x4 a3a = {0,0,0,0}, a3b = {0,0,0,0};
#pragma unroll
    for (int j = 0; j < 8; ++j){
      a3a = __builtin_amdgcn_mfma_f32_16x16x32_bf16(w3f[0][j], fhh[j], a3a, 0, 0, 0);
      a3b = __builtin_amdgcn_mfma_f32_16x16x32_bf16(w3f[1][j], fhh[j], a3b, 0, 0, 0);
    }
    if (ln == hcol){
#pragma unroll
      for (int r4 = 0; r4 < 4; ++r4){
        int d0 = wv*32 + lk*4 + r4;
        h3p[d0] = a3a[r4]; h3p[d0+16] = a3b[r4];
      }
    }
    if (ln == hcol + 8){
#pragma unroll
      for (int r4 = 0; r4 < 4; ++r4){
        int d0 = wv*32 + lk*4 + r4;
        h3q[d0] = a3a[r4]; h3q[d0+16] = a3b[r4];
      }
    }
    BARRIER();
    if (tid < 128) h3row[tid] = fmaxf(h3p[tid] + h3q[tid] + b3L[tid], 0.0f);
    BARRIER();
    if (wv == 0){
      const int l = tid, c = l >> 2, kq = l & 3;
      float p = 0.f;
      if (c < 10){
        const float* wr = &W4L[c*134 + kq*33];
        const float* hr = &h3row[kq*32];
#pragma unroll
        for (int k = 0; k < 32; ++k) p += wr[k]*hr[k];
      }
      p += __shfl_xor(p, 1, 4);
      p += __shfl_xor(p, 2, 4);
      if (c < 10 && kq == 0) ytmp[c] = p + b4L[c];
      asm volatile("s_waitcnt lgkmcnt(0)" ::: "memory");
      float yv = (l < 10) ? ytmp[l] : -INFINITY;
      float mx = yv;
#pragma unroll
      for (int off = 1; off < 16; off <<= 1)
        mx = fmaxf(mx, __shfl_xor(mx, off, 16));
      float ex = (l < 10) ? expf(yv - mx) : 0.0f;
      float sm = ex;
#pragma unroll
      for (int off = 1; off < 16; off <<= 1)
        sm += __shfl_xor(sm, off, 16);
      if (l < 10){
        int orow = (sb < 4) ? (gp*4 + sb) : (128 + gp*4 + (sb - 4));
        outg[((size_t)orow*NT + (NT-1))*NC + l] = yv - (mx + logf(sm));
      }
    }
  }
}

extern "C" void kernel_launch(void* const* d_in, const int* in_sizes, int n_in,
                              void* d_out, int out_size, void* d_ws, size_t ws_size,
                              hipStream_t stream) {
  const float* xg  = (const float*)d_in[0];
  const float* h1i = (const float*)d_in[1];
  const float* h2i = (const float*)d_in[2];
  const float* W1  = (const float*)d_in[3];
  const float* b1  = (const float*)d_in[4];
  const float* W2  = (const float*)d_in[5];
  const float* b2  = (const float*)d_in[6];
  const float* W3  = (const float*)d_in[7];
  const float* b3  = (const float*)d_in[8];
  const float* W4  = (const float*)d_in[9];
  const float* b4  = (const float*)d_in[10];
  float* out = (float*)d_out;
  float* ws  = (float*)d_ws;

  // clear all message epochs (stale epochs from a previous replay would falsely validate)
  hipMemsetAsync(d_ws, 0, 2u * 1024u * 1024u, stream);

  egru_persistent<<<dim3(256), dim3(256), 0, stream>>>(
      xg, h1i, h2i, W1, b1, W2, b2, W3, b3, W4, b4, out, ws);
}

// Round 15
// 1865.454 us; speedup vs baseline: 1.1899x; 1.0802x over previous
//
#include <hip/hip_runtime.h>

#define NT 512   // timesteps
#define FB 128   // feature bins
#define HD 256   // L1 == L2 hidden
#define NC 10
#define NG 32    // groups
#define GR 8     // batch rows per group

typedef __attribute__((ext_vector_type(8))) short bf16x8;
typedef __attribute__((ext_vector_type(4))) float f32x4;
typedef __attribute__((ext_vector_type(4))) unsigned u32x4;

static __device__ __forceinline__ short f2bf(float f){
  union { float f; unsigned u; } v; v.f = f;
  return (short)((v.u + 0x7fffu + ((v.u >> 16) & 1u)) >> 16);  // RNE
}
static __device__ __forceinline__ float bf2f(short h){
  union { unsigned u; float f; } v; v.u = ((unsigned)(unsigned short)h) << 16;
  return v.f;
}
static __device__ __forceinline__ float quantw(float w){
  return fminf(fmaxf(rintf(w * 8.0f) * 0.125f, -1.0f), 1.0f);  // exact in bf16
}
static __device__ __forceinline__ bf16x8 loadqw8(const float* __restrict__ p){
  bf16x8 v;
#pragma unroll
  for (int j = 0; j < 8; ++j) v[j] = f2bf(quantw(p[j]));
  return v;
}
static __device__ __forceinline__ void split8(f32x4 a, f32x4 b, bf16x8& hi, bf16x8& lo){
  float v0[4] = {a[0],a[1],a[2],a[3]}, v1[4] = {b[0],b[1],b[2],b[3]};
#pragma unroll
  for (int j = 0; j < 4; ++j){
    short h = f2bf(v0[j]); hi[j] = h; lo[j] = f2bf(v0[j] - bf2f(h));
  }
#pragma unroll
  for (int j = 0; j < 4; ++j){
    short h = f2bf(v1[j]); hi[4+j] = h; lo[4+j] = f2bf(v1[j] - bf2f(h));
  }
}

// ---- epoch-in-band messaging over sc1 (R9-proven) ----
static __device__ __forceinline__ void st_msg(unsigned* p, short hb, short lb, unsigned ep){
  __attribute__((ext_vector_type(2))) unsigned w;
  w[0] = (((unsigned)(unsigned short)hb) << 16) | ep;
  w[1] = (((unsigned)(unsigned short)lb) << 16) | ep;
  asm volatile("global_store_dwordx2 %0, %1, off sc1" :: "v"(p), "v"(w) : "memory");
}
static __device__ __forceinline__ void gather8(const unsigned* p, unsigned ep, bf16x8& hv, bf16x8& lv){
  u32x4 a, b, c, d;
  for (;;){
    asm volatile("global_load_dwordx4 %0, %4, off sc1\n\t"
                 "global_load_dwordx4 %1, %4, off offset:16 sc1\n\t"
                 "global_load_dwordx4 %2, %4, off offset:32 sc1\n\t"
                 "global_load_dwordx4 %3, %4, off offset:48 sc1\n\t"
                 "s_waitcnt vmcnt(0)"
                 : "=&v"(a), "=&v"(b), "=&v"(c), "=&v"(d) : "v"(p) : "memory");
    unsigned m = (a[0]^ep)|(a[1]^ep)|(a[2]^ep)|(a[3]^ep)
               | (b[0]^ep)|(b[1]^ep)|(b[2]^ep)|(b[3]^ep)
               | (c[0]^ep)|(c[1]^ep)|(c[2]^ep)|(c[3]^ep)
               | (d[0]^ep)|(d[1]^ep)|(d[2]^ep)|(d[3]^ep);
    if ((m & 0xffffu) == 0u) break;
  }
  hv[0]=(short)(a[0]>>16); lv[0]=(short)(a[1]>>16);
  hv[1]=(short)(a[2]>>16); lv[1]=(short)(a[3]>>16);
  hv[2]=(short)(b[0]>>16); lv[2]=(short)(b[1]>>16);
  hv[3]=(short)(b[2]>>16); lv[3]=(short)(b[3]>>16);
  hv[4]=(short)(c[0]>>16); lv[4]=(short)(c[1]>>16);
  hv[5]=(short)(c[2]>>16); lv[5]=(short)(c[3]>>16);
  hv[6]=(short)(d[0]>>16); lv[6]=(short)(d[1]>>16);
  hv[7]=(short)(d[2]>>16); lv[7]=(short)(d[3]>>16);
}
static __device__ __forceinline__ bool chk_unpack(u32x4 a, u32x4 b, u32x4 c, u32x4 d,
                                                  unsigned ep, bf16x8& hv, bf16x8& lv){
  unsigned m = (a[0]^ep)|(a[1]^ep)|(a[2]^ep)|(a[3]^ep)
             | (b[0]^ep)|(b[1]^ep)|(b[2]^ep)|(b[3]^ep)
             | (c[0]^ep)|(c[1]^ep)|(c[2]^ep)|(c[3]^ep)
             | (d[0]^ep)|(d[1]^ep)|(d[2]^ep)|(d[3]^ep);
  if ((m & 0xffffu) != 0u) return false;
  hv[0]=(short)(a[0]>>16); lv[0]=(short)(a[1]>>16);
  hv[1]=(short)(a[2]>>16); lv[1]=(short)(a[3]>>16);
  hv[2]=(short)(b[0]>>16); lv[2]=(short)(b[1]>>16);
  hv[3]=(short)(b[2]>>16); lv[3]=(short)(b[3]>>16);
  hv[4]=(short)(c[0]>>16); lv[4]=(short)(c[1]>>16);
  hv[5]=(short)(c[2]>>16); lv[5]=(short)(c[3]>>16);
  hv[6]=(short)(d[0]>>16); lv[6]=(short)(d[1]>>16);
  hv[7]=(short)(d[2]>>16); lv[7]=(short)(d[3]>>16);
  return true;
}

#define ISSUE_G8(P,A,B,C,D) \
  asm volatile("global_load_dwordx4 %0, %4, off sc1\n\t" \
               "global_load_dwordx4 %1, %4, off offset:16 sc1\n\t" \
               "global_load_dwordx4 %2, %4, off offset:32 sc1\n\t" \
               "global_load_dwordx4 %3, %4, off offset:48 sc1" \
               : "=&v"(A),"=&v"(B),"=&v"(C),"=&v"(D) : "v"(P) : "memory")
#define ISSUE_X2(P,A,B) \
  asm volatile("global_load_dwordx4 %0, %2, off\n\t" \
               "global_load_dwordx4 %1, %2, off offset:16" \
               : "=&v"(A),"=&v"(B) : "v"(P) : "memory")
#define WAITV4(N,A,B,C,D) do{ \
  asm volatile("s_waitcnt vmcnt(" #N ")" : "+v"(A),"+v"(B),"+v"(C),"+v"(D) :: "memory"); \
  __builtin_amdgcn_sched_barrier(0); }while(0)
#define WAITV2(N,A,B) do{ \
  asm volatile("s_waitcnt vmcnt(" #N ")" : "+v"(A),"+v"(B) :: "memory"); \
  __builtin_amdgcn_sched_barrier(0); }while(0)
// keep backup-sample registers alive until their guaranteed-completion point
#define KEEP4(A,B,C,D) asm volatile("" : "+v"(A),"+v"(B),"+v"(C),"+v"(D))
#define BARRIER() do{ asm volatile("s_waitcnt lgkmcnt(0)" ::: "memory"); \
  __builtin_amdgcn_s_barrier(); asm volatile("" ::: "memory"); }while(0)

// 256 blocks x 256 threads, 1 block/CU. gp = bid&31, sb = bid>>5 (same-XCD peers).
// R12 schedule + DOUBLE-SAMPLED gathers: each exchange issues an early sample
// (overlap) and a later backup sample (~0.3-0.6us after peer posts); counted
// waits check the early one, falling back to the backup before the retry loop.
__global__ __launch_bounds__(256, 1)
void egru_persistent(const float* __restrict__ xg,
                     const float* __restrict__ h1ig, const float* __restrict__ h2ig,
                     const float* __restrict__ W1g, const float* __restrict__ b1g,
                     const float* __restrict__ W2g, const float* __restrict__ b2g,
                     const float* __restrict__ W3g, const float* __restrict__ b3g,
                     const float* __restrict__ W4g, const float* __restrict__ b4g,
                     float* __restrict__ outg, float* __restrict__ wsf)
{
  const int tid = threadIdx.x;
  const int gp  = blockIdx.x & 31;
  const int sb  = blockIdx.x >> 5;
  const int wv  = tid >> 6;
  const int ln  = tid & 15;
  const int lk  = (tid >> 4) & 3;
  const int rz  = sb * 32;

  __shared__ __align__(16) short inX [16*128];  // x(t); rows 0-7 hi, 8-15 lo; 256 B/row
  __shared__ __align__(16) short inH1[16*256];  // h1(t); 512 B/row
  __shared__ __align__(16) short inH2[16*256];  // h2(t-1); 512 B/row
  __shared__ float aldsA[64][17];
  __shared__ float aldsB[64][17];
  __shared__ float h1own[32][GR];
  __shared__ float h2own[32][GR];
  __shared__ float h3p[128], h3q[128], h3row[128];
  __shared__ float ytmp[16];
  __shared__ float W4L[1344];                   // skewed: idx = c*134 + (k>>5)*33 + (k&31)
  __shared__ float b1s[64], b2s[64], b3L[128], b4L[10];

  unsigned* h1buf = reinterpret_cast<unsigned*>(wsf);
  unsigned* h2buf = h1buf + 262144;

  bf16x8 w1f[12], w2f[16], w3f[2][8];
  {
    const int arow = (wv < 2) ? (rz + wv*16 + ln) : (256 + rz + (wv-2)*16 + ln);
#pragma unroll
    for (int ks = 0; ks < 12; ++ks) w1f[ks] = loadqw8(W1g + arow*384 + ks*32 + lk*8);
#pragma unroll
    for (int ks = 0; ks < 16; ++ks) w2f[ks] = loadqw8(W2g + arow*512 + ks*32 + lk*8);
#pragma unroll
    for (int tl = 0; tl < 2; ++tl)
#pragma unroll
      for (int ks = 0; ks < 8; ++ks)
        w3f[tl][ks] = loadqw8(W3g + (wv*32 + tl*16 + ln)*256 + ks*32 + lk*8);
  }

  if (tid < 64){
    int grow = (tid < 32) ? (rz + tid) : (256 + rz + (tid - 32));
    b1s[tid] = b1g[grow];
    b2s[tid] = b2g[grow];
  }
  if (tid < 128) b3L[tid] = b3g[tid];
  if (tid < 10)  b4L[tid] = b4g[tid];
  for (int i = tid; i < 1280; i += 256){
    int c = i >> 7, k = i & 127;
    W4L[c*134 + (k>>5)*33 + (k&31)] = quantw(W4g[i]);
  }

  const int ur = tid >> 5, uc = tid & 31;   // (batch row, dim/chunk) mapping, 8x32
  {
    bf16x8 hv, lv;
    const float* p1 = h1ig + (size_t)(gp*GR + ur)*HD + uc*8;
    split8(*(const f32x4*)p1, *(const f32x4*)(p1+4), hv, lv);
    *(bf16x8*)((char*)inH1 + ur*512     + ((uc*16) ^ ((ur&7)<<4))) = hv;
    *(bf16x8*)((char*)inH1 + (ur+8)*512 + ((uc*16) ^ ((ur&7)<<4))) = lv;
    const float* p2 = h2ig + (size_t)(gp*GR + ur)*HD + uc*8;
    split8(*(const f32x4*)p2, *(const f32x4*)(p2+4), hv, lv);
    *(bf16x8*)((char*)inH2 + ur*512     + ((uc*16) ^ ((ur&7)<<4))) = hv;
    *(bf16x8*)((char*)inH2 + (ur+8)*512 + ((uc*16) ^ ((ur&7)<<4))) = lv;
    h1own[uc][ur] = h1ig[(size_t)(gp*GR+ur)*HD + rz + uc];
    h2own[uc][ur] = h2ig[(size_t)(gp*GR+ur)*HD + rz + uc];
  }
  const int xr = tid >> 4, xf = tid & 15;
  const int xrl = xr & 7;                   // clamped row: ALL threads load (uniform vmcnt)
  if (xr < 8){
    const float* px = xg + ((size_t)(gp*GR + xr)*NT + 0)*FB + xf*8;
    bf16x8 hv, lv;
    split8(*(const f32x4*)px, *(const f32x4*)(px+4), hv, lv);
    *(bf16x8*)((char*)inX + xr*256     + ((xf*16) ^ ((xr&7)<<4))) = hv;
    *(bf16x8*)((char*)inX + (xr+8)*256 + ((xf*16) ^ ((xr&7)<<4))) = lv;
  }
  __syncthreads();   // full drain at init boundary (intentional)

  // ---- prologue: acc1 = L1(0) = W1·[x(0); h1(0)] ----
  f32x4 acc1 = {0.f,0.f,0.f,0.f};
#pragma unroll
  for (int j = 0; j < 4; ++j){
    bf16x8 fx = *(bf16x8*)((char*)inX + ln*256 + ((j*64 + lk*16) ^ ((ln&7)<<4)));
    acc1 = __builtin_amdgcn_mfma_f32_16x16x32_bf16(w1f[j], fx, acc1, 0, 0, 0);
  }
#pragma unroll
  for (int j = 0; j < 8; ++j){
    bf16x8 fh = *(bf16x8*)((char*)inH1 + ln*512 + ((j*64 + lk*16) ^ ((ln&7)<<4)));
    acc1 = __builtin_amdgcn_mfma_f32_16x16x32_bf16(w1f[4+j], fh, acc1, 0, 0, 0);
  }

  // backup-sample registers (loop-carried; pending loads may cross iterations)
  u32x4 g1pa, g1pb, g1pc, g1pd, g2pa, g2pb, g2pc, g2pd;

  for (int t = 0; t < NT; ++t){
    unsigned* h1s = h1buf + (unsigned)(t & 1)*131072u + (unsigned)(gp*GR)*512u;
    unsigned* h2s = h2buf + (unsigned)(t & 1)*131072u + (unsigned)(gp*GR)*512u;
    unsigned* h2r = h2buf + (unsigned)((t + 1) & 1)*131072u + (unsigned)(gp*GR)*512u;
    const bool notlast = (t + 1) < NT;   // block-uniform

    // P1: issue h2(t-1) gather, EARLY sample
    u32x4 g2a, g2b, g2c, g2d;
    if (t > 0) ISSUE_G8(&h2r[ur*512 + uc*16], g2a, g2b, g2c, g2d);

    // ---- A1: finish h1(t) ----
#pragma unroll
    for (int r4 = 0; r4 < 4; ++r4)
      aldsA[wv*16 + lk*4 + r4][ln] = acc1[r4];   // C/D: row=(lane>>4)*4+reg, col=lane&15
    BARRIER();
    {
      float az = aldsA[uc][ur]    + aldsA[uc][ur+8]    + b1s[uc];
      float ac = aldsA[32+uc][ur] + aldsA[32+uc][ur+8] + b1s[32+uc];
      float z  = 0.5f*(az/(1.0f+fabsf(az)) + 1.0f);
      float cd = ac/(1.0f+fabsf(ac));
      float hn = z*h1own[uc][ur] + (1.0f - z)*cd;
      h1own[uc][ur] = hn;
      short hb = f2bf(hn), lb = f2bf(hn - bf2f(hb));
      st_msg(&h1s[ur*512 + (rz + uc)*2], hb, lb, (unsigned)(t+1));   // P2
    }

    // P3: h2 BACKUP sample (~0.3us after P1, after A1 work)
    if (t > 0) ISSUE_G8(&h2r[ur*512 + uc*16], g2pa, g2pb, g2pc, g2pd);

    // P4: consume h2(t-1). FIFO: [leftover5][g2x4][stH1][g2'x4] -> vmcnt(5)
    // completes leftovers+g2 on every path (incl. t=1; stale paths drain more).
    if (t > 0){
      WAITV4(5, g2a, g2b, g2c, g2d);
      bf16x8 hv, lv;
      if (!chk_unpack(g2a, g2b, g2c, g2d, (unsigned)t, hv, lv)){
        WAITV4(0, g2pa, g2pb, g2pc, g2pd);
        if (!chk_unpack(g2pa, g2pb, g2pc, g2pd, (unsigned)t, hv, lv))
          gather8(&h2r[ur*512 + uc*16], (unsigned)t, hv, lv);
      }
      *(bf16x8*)((char*)inH2 + ur*512     + ((uc*16) ^ ((ur&7)<<4))) = hv;
      *(bf16x8*)((char*)inH2 + (ur+8)*512 + ((uc*16) ^ ((ur&7)<<4))) = lv;
      KEEP4(g1pa, g1pb, g1pc, g1pd);   // prev iter's g1' completed by the wait above
    }
    BARRIER();   // inH2 visible

    // ---- A-window: fh2 frags once -> L2-h2half ----
    bf16x8 fh2[8];
#pragma unroll
    for (int j = 0; j < 8; ++j)
      fh2[j] = *(bf16x8*)((char*)inH2 + ln*512 + ((j*64 + lk*16) ^ ((ln&7)<<4)));
    f32x4 acc2 = {0.f,0.f,0.f,0.f};
#pragma unroll
    for (int j = 0; j < 8; ++j)
      acc2 = __builtin_amdgcn_mfma_f32_16x16x32_bf16(w2f[8+j], fh2[j], acc2, 0, 0, 0);

    // P6: h1 EARLY sample + x loads (ALL threads; uniform vmcnt)
    u32x4 g1a, g1b, g1c, g1d;
    ISSUE_G8(&h1s[ur*512 + uc*16], g1a, g1b, g1c, g1d);
    f32x4 xa = {0,0,0,0}, xb = {0,0,0,0};
    if (notlast){
      const float* px = xg + ((size_t)(gp*GR + xrl)*NT + (t+1))*FB + xf*8;
      ISSUE_X2(px, xa, xb);
    }

    // P7: head(t-1) for batch row gp*GR+sb (covers g1 flight)
    float outv = 0.f; bool dow = false; size_t oaddr = 0;
    if (t > 0){
      f32x4 acc3a = {0,0,0,0}, acc3b = {0,0,0,0};
#pragma unroll
      for (int j = 0; j < 8; ++j){
        acc3a = __builtin_amdgcn_mfma_f32_16x16x32_bf16(w3f[0][j], fh2[j], acc3a, 0, 0, 0);
        acc3b = __builtin_amdgcn_mfma_f32_16x16x32_bf16(w3f[1][j], fh2[j], acc3b, 0, 0, 0);
      }
      if (ln == sb){
#pragma unroll
        for (int r4 = 0; r4 < 4; ++r4){
          int d0 = wv*32 + lk*4 + r4;
          h3p[d0] = acc3a[r4]; h3p[d0+16] = acc3b[r4];
        }
      }
      if (ln == sb + 8){
#pragma unroll
        for (int r4 = 0; r4 < 4; ++r4){
          int d0 = wv*32 + lk*4 + r4;
          h3q[d0] = acc3a[r4]; h3q[d0+16] = acc3b[r4];
        }
      }
      BARRIER();
      if (tid < 128) h3row[tid] = fmaxf(h3p[tid] + h3q[tid] + b3L[tid], 0.0f);
      BARRIER();
      if (wv == 0){
        const int l = tid, c = l >> 2, kq = l & 3;
        float p = 0.f;
        if (c < 10){
          const float* wr = &W4L[c*134 + kq*33];
          const float* hr = &h3row[kq*32];
#pragma unroll
          for (int k = 0; k < 32; ++k) p += wr[k]*hr[k];
        }
        p += __shfl_xor(p, 1, 4);
        p += __shfl_xor(p, 2, 4);
        if (c < 10 && kq == 0) ytmp[c] = p + b4L[c];
        asm volatile("s_waitcnt lgkmcnt(0)" ::: "memory");
        float yv = (l < 10) ? ytmp[l] : -INFINITY;
        float mx = yv;
#pragma unroll
        for (int off = 1; off < 16; off <<= 1)
          mx = fmaxf(mx, __shfl_xor(mx, off, 16));
        float ex = (l < 10) ? expf(yv - mx) : 0.0f;
        float sm = ex;
#pragma unroll
        for (int off = 1; off < 16; off <<= 1)
          sm += __shfl_xor(sm, off, 16);
        if (l < 10){
          outv = yv - (mx + logf(sm));
          dow = true;
          oaddr = ((size_t)(gp*GR + sb)*NT + (t-1))*NC + l;
        }
      }
    }

    // P8: h1 BACKUP sample (after head; ~0.6us after posts)
    ISSUE_G8(&h1s[ur*512 + uc*16], g1pa, g1pb, g1pc, g1pd);

    // P9: consume h1(t). FIFO: [stH1?, g2'4?, g1x4, x2?, g1'x4]
    // notlast: vmcnt(6) completes through g1 (leaves x2+g1'); last: vmcnt(4).
    {
      if (notlast) WAITV4(6, g1a, g1b, g1c, g1d);
      else         WAITV4(4, g1a, g1b, g1c, g1d);
      bf16x8 hv, lv;
      if (!chk_unpack(g1a, g1b, g1c, g1d, (unsigned)(t+1), hv, lv)){
        WAITV4(0, g1pa, g1pb, g1pc, g1pd);
        if (!chk_unpack(g1pa, g1pb, g1pc, g1pd, (unsigned)(t+1), hv, lv))
          gather8(&h1s[ur*512 + uc*16], (unsigned)(t+1), hv, lv);
      }
      *(bf16x8*)((char*)inH1 + ur*512     + ((uc*16) ^ ((ur&7)<<4))) = hv;
      *(bf16x8*)((char*)inH1 + (ur+8)*512 + ((uc*16) ^ ((ur&7)<<4))) = lv;
      if (t > 0) KEEP4(g2pa, g2pb, g2pc, g2pd);   // g2' completed by the wait above
    }
    if (dow) outg[oaddr] = outv;   // deferred wave0 store
    BARRIER();   // inH1 visible

    // ---- B: fh1 frags once -> L2-h1half; gate h2 ----
    bf16x8 fh1[8];
#pragma unroll
    for (int j = 0; j < 8; ++j)
      fh1[j] = *(bf16x8*)((char*)inH1 + ln*512 + ((j*64 + lk*16) ^ ((ln&7)<<4)));
#pragma unroll
    for (int j = 0; j < 8; ++j)
      acc2 = __builtin_amdgcn_mfma_f32_16x16x32_bf16(w2f[j], fh1[j], acc2, 0, 0, 0);
#pragma unroll
    for (int r4 = 0; r4 < 4; ++r4)
      aldsB[wv*16 + lk*4 + r4][ln] = acc2[r4];
    BARRIER();
    {
      float az = aldsB[uc][ur]    + aldsB[uc][ur+8]    + b2s[uc];
      float ac = aldsB[32+uc][ur] + aldsB[32+uc][ur+8] + b2s[32+uc];
      float z  = 0.5f*(az/(1.0f+fabsf(az)) + 1.0f);
      float cd = ac/(1.0f+fabsf(ac));
      float hn = z*h2own[uc][ur] + (1.0f - z)*cd;
      h2own[uc][ur] = hn;
      short hb = f2bf(hn), lb = f2bf(hn - bf2f(hb));
      st_msg(&h2s[ur*512 + (rz + uc)*2], hb, lb, (unsigned)(t+1));   // P11
    }

    // P12: consume x(t+1). vmcnt(5) completes x on all waves/paths.
    if (notlast){
      WAITV2(5, xa, xb);
      if (xr < 8){
        bf16x8 hv, lv;
        split8(xa, xb, hv, lv);
        *(bf16x8*)((char*)inX + xr*256     + ((xf*16) ^ ((xr&7)<<4))) = hv;
        *(bf16x8*)((char*)inX + (xr+8)*256 + ((xf*16) ^ ((xr&7)<<4))) = lv;
      }
      BARRIER();   // inX visible

      // ---- B-window: L1(t+1) = x-part (LDS) + h1-part (fh1 regs, reused) ----
      f32x4 a1n = {0.f,0.f,0.f,0.f};
#pragma unroll
      for (int j = 0; j < 4; ++j){
        bf16x8 fx = *(bf16x8*)((char*)inX + ln*256 + ((j*64 + lk*16) ^ ((ln&7)<<4)));
        a1n = __builtin_amdgcn_mfma_f32_16x16x32_bf16(w1f[j], fx, a1n, 0, 0, 0);
      }
#pragma unroll
      for (int j = 0; j < 8; ++j)
        a1n = __builtin_amdgcn_mfma_f32_16x16x32_bf16(w1f[4+j], fh1[j], a1n, 0, 0, 0);
      acc1 = a1n;
    }
  }

  // ---- epilogue: gather h2(NT-1) (epoch NT), head(NT-1) ----
  {
    unsigned* h2e = h2buf + (unsigned)((NT-1) & 1)*131072u + (unsigned)(gp*GR)*512u;
    bf16x8 hv, lv;
    gather8(&h2e[ur*512 + uc*16], (unsigned)NT, hv, lv);   // drains vmcnt(0) internally
    KEEP4(g1pa, g1pb, g1pc, g1pd);                         // last iter's g1' completed
    *(bf16x8*)((char*)inH2 + ur*512     + ((uc*16) ^ ((ur&7)<<4))) = hv;
    *(bf16x8*)((char*)inH2 + (ur+8)*512 + ((uc*16) ^ ((ur&7)<<4))) = lv;
  }
  BARRIER();
  {
    bf16x8 fh2[8];
#pragma unroll
    for (int j = 0; j < 8; ++j)
      fh2[j] = *(bf16x8*)((char*)inH2 + ln*512 + ((j*64 + lk*16) ^ ((ln&7)<<4)));
    f32x4 acc3a = {0,0,0,0}, acc3b = {0,0,0,0};
#pragma unroll
    for (int j = 0; j < 8; ++j){
      acc3a = __builtin_amdgcn_mfma_f32_16x16x32_bf16(w3f[0][j], fh2[j], acc3a, 0, 0, 0);
      acc3b = __builtin_amdgcn_mfma_f32_16x16x32_bf16(w3f[1][j], fh2[j], acc3b, 0, 0, 0);
    }
    if (ln == sb){
#pragma unroll
      for (int r4 = 0; r4 < 4; ++r4){
        int d0 = wv*32 + lk*4 + r4;
        h3p[d0] = acc3a[r4]; h3p[d0+16] = acc3b[r4];
      }
    }
    if (ln == sb + 8){
#pragma unroll
      for (int r4 = 0; r4 < 4; ++r4){
        int d0 = wv*32 + lk*4 + r4;
        h3q[d0] = acc3a[r4]; h3q[d0+16] = acc3b[r4];
      }
    }
    BARRIER();
    if (tid < 128) h3row[tid] = fmaxf(h3p[tid] + h3q[tid] + b3L[tid], 0.0f);
    BARRIER();
    if (wv == 0){
      const int l = tid, c = l >> 2, kq = l & 3;
      float p = 0.f;
      if (c < 10){
        const float* wr = &W4L[c*134 + kq*33];
        const float* hr = &h3row[kq*32];
#pragma unroll
        for (int k = 0; k < 32; ++k) p += wr[k]*hr[k];
      }
      p += __shfl_xor(p, 1, 4);
      p += __shfl_xor(p, 2, 4);
      if (c < 10 && kq == 0) ytmp[c] = p + b4L[c];
      asm volatile("s_waitcnt lgkmcnt(0)" ::: "memory");
      float yv = (l < 10) ? ytmp[l] : -INFINITY;
      float mx = yv;
#pragma unroll
      for (int off = 1; off < 16; off <<= 1)
        mx = fmaxf(mx, __shfl_xor(mx, off, 16));
      float ex = (l < 10) ? expf(yv - mx) : 0.0f;
      float sm = ex;
#pragma unroll
      for (int off = 1; off < 16; off <<= 1)
        sm += __shfl_xor(sm, off, 16);
      if (l < 10)
        outg[((size_t)(gp*GR + sb)*NT + (NT-1))*NC + l] = yv - (mx + logf(sm));
    }
  }
}

extern "C" void kernel_launch(void* const* d_in, const int* in_sizes, int n_in,
                              void* d_out, int out_size, void* d_ws, size_t ws_size,
                              hipStream_t stream) {
  const float* xg  = (const float*)d_in[0];
  const float* h1i = (const float*)d_in[1];
  const float* h2i = (const float*)d_in[2];
  const float* W1  = (const float*)d_in[3];
  const float* b1  = (const float*)d_in[4];
  const float* W2  = (const float*)d_in[5];
  const float* b2  = (const float*)d_in[6];
  const float* W3  = (const float*)d_in[7];
  const float* b3  = (const float*)d_in[8];
  const float* W4  = (const float*)d_in[9];
  const float* b4  = (const float*)d_in[10];
  float* out = (float*)d_out;
  float* ws  = (float*)d_ws;

  // clear all message epochs (stale epochs from a previous replay would falsely validate)
  hipMemsetAsync(d_ws, 0, 2u * 1024u * 1024u, stream);

  egru_persistent<<<dim3(256), dim3(256), 0, stream>>>(
      xg, h1i, h2i, W1, b1, W2, b2, W3, b3, W4, b4, out, ws);
}